// Round 2
// baseline (704.796 us; speedup 1.0000x reference)
//
#include <hip/hip_runtime.h>
#include <stdint.h>

typedef __attribute__((ext_vector_type(4))) float f32x4;
typedef __attribute__((ext_vector_type(4))) float float4v;
typedef __attribute__((ext_vector_type(8))) short short8;
typedef __attribute__((ext_vector_type(4))) unsigned short ushort4v;

// ---------- helpers ----------

__device__ __forceinline__ unsigned short f2bf(float f) {
  union { float f; unsigned u; } cv; cv.f = f;
  return (unsigned short)((cv.u + 0x7fffu + ((cv.u >> 16) & 1u)) >> 16);
}

__device__ __forceinline__ void gload_lds16(const unsigned short* g, unsigned short* lds) {
  __builtin_amdgcn_global_load_lds(
      (const __attribute__((address_space(1))) void*)g,
      (__attribute__((address_space(3))) void*)lds, 16, 0, 0);
}

__device__ __forceinline__ void mfma_bf16(f32x4& acc, short8 a, short8 b) {
  asm("v_mfma_f32_16x16x32_bf16 %0, %1, %2, %0" : "+v"(acc) : "v"(a), "v"(b));
}

// ---------- kernel 1: x(fp32 [N][D]) -> xt(bf16 [D][N]) and xb(bf16 [N][D]) ----------

__global__ __launch_bounds__(256) void transpose_convert(
    const float* __restrict__ x, unsigned short* __restrict__ xt,
    unsigned short* __restrict__ xb) {
  const int D = 4096, N = 8192;
  __shared__ float tile[32][33];
  int dx = blockIdx.x * 32 + threadIdx.x;
  int ny = blockIdx.y * 32 + threadIdx.y;
#pragma unroll
  for (int j = 0; j < 32; j += 8) {
    float v = x[(size_t)(ny + j) * D + dx];
    tile[threadIdx.y + j][threadIdx.x] = v;
    xb[(size_t)(ny + j) * D + dx] = f2bf(v);
  }
  __syncthreads();
  int dy = blockIdx.x * 32 + threadIdx.y;
  int nx = blockIdx.y * 32 + threadIdx.x;
#pragma unroll
  for (int j = 0; j < 32; j += 8)
    xt[(size_t)(dy + j) * N + nx] = f2bf(tile[threadIdx.x][threadIdx.y + j]);
}

// ---------- 256x256-tile GEMM: C[M][N] = A[M][K] * B[N][K]^T (bf16 in, fp32 out) ----------
// 8 waves (2Mx4N), BK=32 per phase, 4-slot LDS ring per operand (128 KiB total),
// prefetch distance 3 phases -> steady-state s_waitcnt vmcnt(12) (counted, never 0),
// raw s_barrier + sched_barrier pins, setprio around MFMA cluster,
// XOR-swizzled LDS (byte ^= (row&3)<<4) with inverse-permuted global staging source.

__global__ __launch_bounds__(512, 2) void gemm256(
    const unsigned short* __restrict__ A, const unsigned short* __restrict__ B,
    float* __restrict__ C, int M, int N, int K) {
  __shared__ __align__(16) unsigned short As[4 * 8192];  // 64 KiB: 4 slots of [256][32]
  __shared__ __align__(16) unsigned short Bs[4 * 8192];  // 64 KiB

  const int mtiles = M >> 8;
  const int nwg = gridDim.x;
  const int bid = blockIdx.x;
  const int swz = (bid & 7) * (nwg >> 3) + (bid >> 3);   // XCD swizzle (nwg % 8 == 0)
  const int tm = swz % mtiles, tn = swz / mtiles;
  const size_t m0 = (size_t)tm * 256, n0 = (size_t)tn * 256;

  const int t = threadIdx.x;
  const int w = t >> 6, lane = t & 63;
  const int wr = w >> 2, wc = w & 3;                      // 2 M-waves x 4 N-waves
  const int l15 = lane & 15, l4 = lane >> 4;

  // --- staging addressing: chunk ch covers LDS bytes [ch*16, ch*16+16) of a slot ---
  // LDS logical: [256 rows][32 k] bf16, swizzled: byte ^= ((row&3)<<4).
  // Linear dest chunk (row, c) must be fed from global k-chunk c ^ (row&3).
  const int srow = t >> 2;                                // 0..127 (round 0)
  const int scol = ((t & 3) ^ (srow & 3)) * 8;            // permuted k-element offset
  const unsigned short* gA0 = A + (m0 + srow) * (size_t)K + scol;
  const unsigned short* gA1 = A + (m0 + 128 + srow) * (size_t)K + scol;
  const unsigned short* gB0 = B + (n0 + srow) * (size_t)K + scol;
  const unsigned short* gB1 = B + (n0 + 128 + srow) * (size_t)K + scol;
  const int dst0 = w * 512;                               // wave-uniform LDS elem offset
  const int dst1 = 4096 + w * 512;

  // --- ds_read addressing (swizzled): row = base + (lane&15), k-chunk = (l>>4)^(row&3) ---
  const int swzc = ((l4 ^ (lane & 3)) * 8);
  const int laneA = (wr * 128 + l15) * 32 + swzc;         // + m*512 per frag
  const int laneB = (wc * 64 + l15) * 32 + swzc;          // + n*512 per frag

  f32x4 acc[8][4] = {};

  auto stage = [&](int h) {
    const size_t ko = (size_t)h * 32;
    unsigned short* sa = As + (h & 3) * 8192;
    unsigned short* sb = Bs + (h & 3) * 8192;
    gload_lds16(gA0 + ko, sa + dst0);
    gload_lds16(gA1 + ko, sa + dst1);
    gload_lds16(gB0 + ko, sb + dst0);
    gload_lds16(gB1 + ko, sb + dst1);
  };

  auto compute = [&](int h) {
    const unsigned short* pa = As + (h & 3) * 8192 + laneA;
    const unsigned short* pb = Bs + (h & 3) * 8192 + laneB;
    short8 af[8], bf[4];
#pragma unroll
    for (int m = 0; m < 8; ++m) af[m] = *reinterpret_cast<const short8*>(pa + m * 512);
#pragma unroll
    for (int n = 0; n < 4; ++n) bf[n] = *reinterpret_cast<const short8*>(pb + n * 512);
    __builtin_amdgcn_s_setprio(1);
#pragma unroll
    for (int m = 0; m < 8; ++m)
#pragma unroll
      for (int n = 0; n < 4; ++n) mfma_bf16(acc[m][n], af[m], bf[n]);
    __builtin_amdgcn_s_setprio(0);
  };

  const int Nph = K >> 5;  // >= 4 always here
  stage(0); stage(1); stage(2);           // 12 loads in flight

  for (int h = 0; h < Nph - 3; ++h) {
    __builtin_amdgcn_sched_barrier(0);    // pin stage after prior end-barrier
    stage(h + 3);                          // 16 in flight
    asm volatile("s_waitcnt vmcnt(12)" ::: "memory");  // half h landed
    __builtin_amdgcn_s_barrier();
    __builtin_amdgcn_sched_barrier(0);
    compute(h);
    __builtin_amdgcn_sched_barrier(0);
    __builtin_amdgcn_s_barrier();         // all waves done reading slot h&3
  }
  // tail: drain 12 -> 8 -> 4 -> 0
  asm volatile("s_waitcnt vmcnt(8)" ::: "memory");
  __builtin_amdgcn_s_barrier(); __builtin_amdgcn_sched_barrier(0);
  compute(Nph - 3);
  __builtin_amdgcn_sched_barrier(0); __builtin_amdgcn_s_barrier();
  asm volatile("s_waitcnt vmcnt(4)" ::: "memory");
  __builtin_amdgcn_s_barrier(); __builtin_amdgcn_sched_barrier(0);
  compute(Nph - 2);
  __builtin_amdgcn_sched_barrier(0); __builtin_amdgcn_s_barrier();
  asm volatile("s_waitcnt vmcnt(0)" ::: "memory");
  __builtin_amdgcn_s_barrier(); __builtin_amdgcn_sched_barrier(0);
  compute(Nph - 1);

  // epilogue: frag (m,n): row = m0+wr*128+m*16+(lane>>4)*4+r, col = n0+wc*64+n*16+(lane&15)
#pragma unroll
  for (int m = 0; m < 8; ++m) {
    size_t r0 = m0 + wr * 128 + m * 16 + l4 * 4;
#pragma unroll
    for (int n = 0; n < 4; ++n) {
      size_t c0 = n0 + wc * 64 + n * 16 + l15;
      float* cp = C + r0 * (size_t)N + c0;
#pragma unroll
      for (int r = 0; r < 4; ++r) cp[(size_t)r * N] = acc[m][n][r];
    }
  }
}

// ---------- kernel 3: column softmax via Gram symmetry -> bt (bf16, bt[j][i]=b[i][j]) ----------

__global__ __launch_bounds__(256) void softmax_rows(
    const float* __restrict__ a, unsigned short* __restrict__ bt) {
  const int D = 4096;
  const int row = blockIdx.x;
  const float* ar = a + (size_t)row * D;
  unsigned short* br = bt + (size_t)row * D;
  const int t = threadIdx.x;

  float4v v[4];
  float mx = -3.4e38f;
#pragma unroll
  for (int p = 0; p < 4; ++p) {
    v[p] = *reinterpret_cast<const float4v*>(&ar[p * 1024 + t * 4]);
#pragma unroll
    for (int q = 0; q < 4; ++q) mx = fmaxf(mx, v[p][q]);
  }
#pragma unroll
  for (int o = 32; o >= 1; o >>= 1) mx = fmaxf(mx, __shfl_xor(mx, o));
  __shared__ float redm[4], reds[4];
  if ((t & 63) == 0) redm[t >> 6] = mx;
  __syncthreads();
  mx = fmaxf(fmaxf(redm[0], redm[1]), fmaxf(redm[2], redm[3]));

  float e[16];
  float s = 0.f;
#pragma unroll
  for (int p = 0; p < 4; ++p)
#pragma unroll
    for (int q = 0; q < 4; ++q) {
      float ev = __expf(v[p][q] - mx);
      e[p * 4 + q] = ev;
      s += ev;
    }
#pragma unroll
  for (int o = 32; o >= 1; o >>= 1) s += __shfl_xor(s, o);
  if ((t & 63) == 0) reds[t >> 6] = s;
  __syncthreads();
  s = reds[0] + reds[1] + reds[2] + reds[3];
  float inv = 1.0f / s;

#pragma unroll
  for (int p = 0; p < 4; ++p) {
    ushort4v o4;
#pragma unroll
    for (int q = 0; q < 4; ++q) o4[q] = f2bf(e[p * 4 + q] * inv);
    *reinterpret_cast<ushort4v*>(&br[p * 1024 + t * 4]) = o4;
  }
}

// ---------- launch ----------

extern "C" void kernel_launch(void* const* d_in, const int* in_sizes, int n_in,
                              void* d_out, int out_size, void* d_ws, size_t ws_size,
                              hipStream_t stream) {
  const int N = 8192, D = 4096;
  const float* x = (const float*)d_in[0];
  float* out = (float*)d_out;
  uint8_t* ws = (uint8_t*)d_ws;

  unsigned short* xt = (unsigned short*)ws;                           // 64 MB bf16 [D][N]
  unsigned short* xb = (unsigned short*)(ws + ((size_t)64 << 20));    // 64 MB bf16 [N][D]
  unsigned short* bt = (unsigned short*)(ws + ((size_t)128 << 20));   // 32 MB bf16 [D][D]
  float* a = out;  // Gram matrix staged in d_out (overwritten by GEMM2)

  transpose_convert<<<dim3(D / 32, N / 32), dim3(32, 8), 0, stream>>>(x, xt, xb);
  gemm256<<<dim3((D / 256) * (D / 256)), dim3(512), 0, stream>>>(xt, xt, a, D, D, N);
  softmax_rows<<<dim3(D), dim3(256), 0, stream>>>(a, bt);
  gemm256<<<dim3((N / 256) * (D / 256)), dim3(512), 0, stream>>>(xb, bt, out, N, D, D);
}

// Round 5
// 552.503 us; speedup vs baseline: 1.2756x; 1.2756x over previous
//
#include <hip/hip_runtime.h>
#include <stdint.h>

typedef __attribute__((ext_vector_type(4))) float f32x4;
typedef __attribute__((ext_vector_type(4))) float float4v;
typedef __attribute__((ext_vector_type(8))) short short8;
typedef __attribute__((ext_vector_type(4))) unsigned short ushort4v;

// ---------- helpers ----------

__device__ __forceinline__ unsigned short f2bf(float f) {
  union { float f; unsigned u; } cv; cv.f = f;
  return (unsigned short)((cv.u + 0x7fffu + ((cv.u >> 16) & 1u)) >> 16);
}

__device__ __forceinline__ void gload_lds16(const unsigned short* g, unsigned short* lds) {
  __builtin_amdgcn_global_load_lds(
      (const __attribute__((address_space(1))) void*)g,
      (__attribute__((address_space(3))) void*)lds, 16, 0, 0);
}

__device__ __forceinline__ void mfma_bf16(f32x4& acc, short8 a, short8 b) {
  asm("v_mfma_f32_16x16x32_bf16 %0, %1, %2, %0" : "+v"(acc) : "v"(a), "v"(b));
}

__device__ __forceinline__ void memfence_ir() { asm volatile("" ::: "memory"); }

// ---------- kernel 1: x(fp32 [N][D]) -> xt(bf16 [D][N]) and xb(bf16 [N][D]) ----------

__global__ __launch_bounds__(256) void transpose_convert(
    const float* __restrict__ x, unsigned short* __restrict__ xt,
    unsigned short* __restrict__ xb) {
  const int D = 4096, N = 8192;
  __shared__ float tile[32][33];
  int dx = blockIdx.x * 32 + threadIdx.x;
  int ny = blockIdx.y * 32 + threadIdx.y;
#pragma unroll
  for (int j = 0; j < 32; j += 8) {
    float v = x[(size_t)(ny + j) * D + dx];
    tile[threadIdx.y + j][threadIdx.x] = v;
    xb[(size_t)(ny + j) * D + dx] = f2bf(v);
  }
  __syncthreads();
  int dy = blockIdx.x * 32 + threadIdx.y;
  int nx = blockIdx.y * 32 + threadIdx.x;
#pragma unroll
  for (int j = 0; j < 32; j += 8)
    xt[(size_t)(dy + j) * N + nx] = f2bf(tile[threadIdx.x][threadIdx.y + j]);
}

// ---------- 256x256 GEMM, 8-phase, quarter-granularity staging ----------
// BK=64, 2-buffer LDS (128 KiB), 8 waves (2M x 4N), per-wave 128x64 out in 4
// quadrants. Read map (rows of the [256][64] LDS tiles, across all waves):
//   A rows 0-63 & 128-191   last read P0   -> staged (tt+2) at P1
//   A rows 64-127 & 192-255 last read P2   -> staged (tt+2) at P3
//   B all quarters          last read P1   -> staged (tt+2) at P2
// Each stage-unit = ONE global_load_lds = 64 rows (512 lanes x 16B).
// vmcnt(8) once per tile at P3: completes tile tt+1's 8 loads, leaves tile
// tt+2's 8 in flight. Every stage is issued after the barrier following its
// region's last read (barrier arrival implies readers' lgkmcnt(0) passed).
// Swizzle: LDS[row][c] = global k-chunk c ^ (row&7), both-sides involution.

template <int MH, int NH>
__device__ __forceinline__ void quad(f32x4 (&acc)[8][4], short8 (&af)[4][2],
                                     short8 (&bf)[2][2]) {
  __builtin_amdgcn_s_setprio(1);
#pragma unroll
  for (int m = 0; m < 4; ++m)
#pragma unroll
    for (int n = 0; n < 2; ++n)
#pragma unroll
      for (int ks = 0; ks < 2; ++ks)
        mfma_bf16(acc[MH * 4 + m][NH * 2 + n], af[m][ks], bf[n][ks]);
  __builtin_amdgcn_s_setprio(0);
}

__global__ __launch_bounds__(512, 2) void gemm256(
    const unsigned short* __restrict__ A, const unsigned short* __restrict__ B,
    float* __restrict__ C, int M, int N, int K) {
  __shared__ __align__(16) unsigned short As[2 * 16384];  // 2 buf x [256][64]
  __shared__ __align__(16) unsigned short Bs[2 * 16384];

  const int mtiles = M >> 8;
  const int nwg = gridDim.x;
  const int bid = blockIdx.x;
  const int swz = (bid & 7) * (nwg >> 3) + (bid >> 3);  // nwg % 8 == 0
  const int tm = swz % mtiles, tn = swz / mtiles;
  const size_t m0 = (size_t)tm * 256, n0 = (size_t)tn * 256;
  const size_t Kz = (size_t)K, Nz = (size_t)N;

  const int t = threadIdx.x;
  const int w = t >> 6, lane = t & 63;
  const int wr = w >> 2, wc = w & 3;
  const int l15 = lane & 15, l4 = lane >> 4;

  // staging: one gload = 64 rows; thread t owns 16B chunk t of the region:
  // region row = t>>3 (0..63), chunk col = t&7, source k-chunk = col ^ (row&7).
  const int srow = t >> 3;
  const int cg = ((t & 7) ^ (srow & 7)) * 8;
  const unsigned short* gA = A + (m0 + srow) * Kz + cg;
  const unsigned short* gB = B + (n0 + srow) * Kz + cg;

  auto stgA = [&](int r0, int tt) {  // rows [r0, r0+64) of A tile tt
    gload_lds16(gA + (size_t)r0 * Kz + (size_t)tt * 64,
                (unsigned short*)As + (tt & 1) * 16384 + r0 * 64 + w * 512);
  };
  auto stgB = [&](int r0, int tt) {
    gload_lds16(gB + (size_t)r0 * Kz + (size_t)tt * 64,
                (unsigned short*)Bs + (tt & 1) * 16384 + r0 * 64 + w * 512);
  };

  // frag reads (swizzled): chunk' = (ks*4 + l4) ^ (row&7), row&7 == l15&7
  const int c0s = (l4 ^ (l15 & 7)) * 8;
  const int c1s = ((4 + l4) ^ (l15 & 7)) * 8;
  const int aRow = (wr * 128 + l15) * 64;
  const int bRow = (wc * 64 + l15) * 64;

  auto loadA = [&](const unsigned short* Ab, int mh, short8 (&af)[4][2]) {
#pragma unroll
    for (int m = 0; m < 4; ++m) {
      const unsigned short* p = Ab + aRow + (mh * 64 + m * 16) * 64;
      af[m][0] = *reinterpret_cast<const short8*>(p + c0s);
      af[m][1] = *reinterpret_cast<const short8*>(p + c1s);
    }
  };
  auto loadB = [&](const unsigned short* Bb, int nh, short8 (&bf)[2][2]) {
#pragma unroll
    for (int n = 0; n < 2; ++n) {
      const unsigned short* p = Bb + bRow + (nh * 32 + n * 16) * 64;
      bf[n][0] = *reinterpret_cast<const short8*>(p + c0s);
      bf[n][1] = *reinterpret_cast<const short8*>(p + c1s);
    }
  };

  auto barMid = [&]() {
    __builtin_amdgcn_sched_barrier(0);
    __builtin_amdgcn_s_barrier();
    asm volatile("s_waitcnt lgkmcnt(0)" ::: "memory");
    __builtin_amdgcn_sched_barrier(0);
  };
  auto barEnd = [&]() {
    __builtin_amdgcn_sched_barrier(0);
    __builtin_amdgcn_s_barrier();
  };

  f32x4 acc[8][4] = {};
  short8 af[4][2], bf0[2][2], bf1[2][2];

  const int T = K >> 6;
  // prologue: tile 0 (8 gloads) | fence | tile 1 (8 gloads) | vmcnt(8)
  stgA(0, 0); stgA(64, 0); stgA(128, 0); stgA(192, 0);
  stgB(0, 0); stgB(64, 0); stgB(128, 0); stgB(192, 0);
  memfence_ir();
  stgA(0, 1); stgA(64, 1); stgA(128, 1); stgA(192, 1);
  stgB(0, 1); stgB(64, 1); stgB(128, 1); stgB(192, 1);
  asm volatile("s_waitcnt vmcnt(8)" ::: "memory");  // tile 0 fully landed
  __builtin_amdgcn_s_barrier();

  for (int tt = 0; tt < T; ++tt) {
    const unsigned short* Ab = (const unsigned short*)As + (tt & 1) * 16384;
    const unsigned short* Bb = (const unsigned short*)Bs + (tt & 1) * 16384;
    // P0: reads A-mh0 (8) + B-nh0 (4); no stage
    loadA(Ab, 0, af);
    loadB(Bb, 0, bf0);
    barMid();
    quad<0, 0>(acc, af, bf0);
    barEnd();
    // P1: reads B-nh1 (4); stage A rows 0-63 & 128-191 of tt+2 (last read: P0)
    loadB(Bb, 1, bf1);
    if (tt + 2 < T) { stgA(0, tt + 2); stgA(128, tt + 2); }
    barMid();
    quad<0, 1>(acc, af, bf1);
    barEnd();
    // P2: reads A-mh1 (8); stage all B quarters of tt+2 (last read: P1)
    loadA(Ab, 1, af);
    if (tt + 2 < T) { stgB(0, tt + 2); stgB(64, tt + 2); stgB(128, tt + 2); stgB(192, tt + 2); }
    barMid();
    quad<1, 1>(acc, af, bf1);
    barEnd();
    // P3: no reads; stage A rows 64-127 & 192-255 of tt+2 (last read: P2)
    if (tt + 2 < T) {
      stgA(64, tt + 2); stgA(192, tt + 2);
      asm volatile("s_waitcnt vmcnt(8)" ::: "memory");  // tile tt+1 landed
    } else if (tt + 1 < T) {
      asm volatile("s_waitcnt vmcnt(0)" ::: "memory");  // tail drain
    }
    barMid();
    quad<1, 0>(acc, af, bf0);
    barEnd();
  }

  // epilogue: row = m0+wr*128+mh*64+m*16+l4*4+r, col = n0+wc*64+nh*32+n*16+l15
#pragma unroll
  for (int mh = 0; mh < 2; ++mh)
#pragma unroll
    for (int m = 0; m < 4; ++m) {
      size_t r0 = m0 + wr * 128 + mh * 64 + m * 16 + l4 * 4;
#pragma unroll
      for (int nh = 0; nh < 2; ++nh)
#pragma unroll
        for (int n = 0; n < 2; ++n) {
          size_t c0 = n0 + wc * 64 + nh * 32 + n * 16 + l15;
          float* cp = C + r0 * Nz + c0;
#pragma unroll
          for (int r = 0; r < 4; ++r) cp[(size_t)r * Nz] = acc[mh * 4 + m][nh * 2 + n][r];
        }
    }
}

// ---------- kernel 3: column softmax via Gram symmetry -> bt (bf16, bt[j][i]=b[i][j]) ----------

__global__ __launch_bounds__(256) void softmax_rows(
    const float* __restrict__ a, unsigned short* __restrict__ bt) {
  const int D = 4096;
  const int row = blockIdx.x;
  const float* ar = a + (size_t)row * D;
  unsigned short* br = bt + (size_t)row * D;
  const int t = threadIdx.x;

  float4v v[4];
  float mx = -3.4e38f;
#pragma unroll
  for (int p = 0; p < 4; ++p) {
    v[p] = *reinterpret_cast<const float4v*>(&ar[p * 1024 + t * 4]);
#pragma unroll
    for (int q = 0; q < 4; ++q) mx = fmaxf(mx, v[p][q]);
  }
#pragma unroll
  for (int o = 32; o >= 1; o >>= 1) mx = fmaxf(mx, __shfl_xor(mx, o));
  __shared__ float redm[4], reds[4];
  if ((t & 63) == 0) redm[t >> 6] = mx;
  __syncthreads();
  mx = fmaxf(fmaxf(redm[0], redm[1]), fmaxf(redm[2], redm[3]));

  float e[16];
  float s = 0.f;
#pragma unroll
  for (int p = 0; p < 4; ++p)
#pragma unroll
    for (int q = 0; q < 4; ++q) {
      float ev = __expf(v[p][q] - mx);
      e[p * 4 + q] = ev;
      s += ev;
    }
#pragma unroll
  for (int o = 32; o >= 1; o >>= 1) s += __shfl_xor(s, o);
  if ((t & 63) == 0) reds[t >> 6] = s;
  __syncthreads();
  s = reds[0] + reds[1] + reds[2] + reds[3];
  float inv = 1.0f / s;

#pragma unroll
  for (int p = 0; p < 4; ++p) {
    ushort4v o4;
#pragma unroll
    for (int q = 0; q < 4; ++q) o4[q] = f2bf(e[p * 4 + q] * inv);
    *reinterpret_cast<ushort4v*>(&br[p * 1024 + t * 4]) = o4;
  }
}

// ---------- launch ----------

extern "C" void kernel_launch(void* const* d_in, const int* in_sizes, int n_in,
                              void* d_out, int out_size, void* d_ws, size_t ws_size,
                              hipStream_t stream) {
  const int N = 8192, D = 4096;
  const float* x = (const float*)d_in[0];
  float* out = (float*)d_out;
  uint8_t* ws = (uint8_t*)d_ws;

  unsigned short* xt = (unsigned short*)ws;                           // 64 MB bf16 [D][N]
  unsigned short* xb = (unsigned short*)(ws + ((size_t)64 << 20));    // 64 MB bf16 [N][D]
  unsigned short* bt = (unsigned short*)(ws + ((size_t)128 << 20));   // 32 MB bf16 [D][D]
  float* a = out;  // Gram matrix staged in d_out (overwritten by GEMM2)

  transpose_convert<<<dim3(D / 32, N / 32), dim3(32, 8), 0, stream>>>(x, xt, xb);
  gemm256<<<dim3((D / 256) * (D / 256)), dim3(512), 0, stream>>>(xt, xt, a, D, D, N);
  softmax_rows<<<dim3(D), dim3(256), 0, stream>>>(a, bt);
  gemm256<<<dim3((N / 256) * (D / 256)), dim3(512), 0, stream>>>(xb, bt, out, N, D, D);
}

// Round 6
// 551.979 us; speedup vs baseline: 1.2769x; 1.0009x over previous
//
#include <hip/hip_runtime.h>
#include <stdint.h>

typedef __attribute__((ext_vector_type(4))) float f32x4;
typedef __attribute__((ext_vector_type(4))) float float4v;
typedef __attribute__((ext_vector_type(8))) short short8;
typedef __attribute__((ext_vector_type(4))) unsigned short ushort4v;

// ---------- helpers ----------

__device__ __forceinline__ unsigned short f2bf(float f) {
  union { float f; unsigned u; } cv; cv.f = f;
  return (unsigned short)((cv.u + 0x7fffu + ((cv.u >> 16) & 1u)) >> 16);
}

__device__ __forceinline__ void gload_lds16(const unsigned short* g, unsigned short* lds) {
  __builtin_amdgcn_global_load_lds(
      (const __attribute__((address_space(1))) void*)g,
      (__attribute__((address_space(3))) void*)lds, 16, 0, 0);
}

__device__ __forceinline__ void mfma_bf16(f32x4& acc, short8 a, short8 b) {
  asm("v_mfma_f32_16x16x32_bf16 %0, %1, %2, %0" : "+v"(acc) : "v"(a), "v"(b));
}

__device__ __forceinline__ void memfence_ir() { asm volatile("" ::: "memory"); }

// ---------- kernel 1: x(fp32 [N][D]) -> xt(bf16 [D][N]) and xb(bf16 [N][D]) ----------

__global__ __launch_bounds__(256) void transpose_convert(
    const float* __restrict__ x, unsigned short* __restrict__ xt,
    unsigned short* __restrict__ xb) {
  const int D = 4096, N = 8192;
  __shared__ float tile[32][33];
  int dx = blockIdx.x * 32 + threadIdx.x;
  int ny = blockIdx.y * 32 + threadIdx.y;
#pragma unroll
  for (int j = 0; j < 32; j += 8) {
    float v = x[(size_t)(ny + j) * D + dx];
    tile[threadIdx.y + j][threadIdx.x] = v;
    xb[(size_t)(ny + j) * D + dx] = f2bf(v);
  }
  __syncthreads();
  int dy = blockIdx.x * 32 + threadIdx.y;
  int nx = blockIdx.y * 32 + threadIdx.x;
#pragma unroll
  for (int j = 0; j < 32; j += 8)
    xt[(size_t)(dy + j) * N + nx] = f2bf(tile[threadIdx.x][threadIdx.y + j]);
}

// ---------- 256x256 GEMM, 8-phase, balanced reads (8/4/8/4) ----------
// BK=64, 2-buffer LDS (128 KiB), 8 waves (2M x 4N), per-wave 128x64 out in 4
// quadrants. ds_read distribution: P0: A-mh0 (8); P1: B-nh1 (4); P2: A-mh1 (8);
// P3: B-nh0 of NEXT tile (4, post-vmcnt(8)+barrier, overlapping P3's MFMA).
// Staging (64-row units, strictly after the barrier following the region's
// last read): A rows{0-63,128-191}@P1, all B@P2, A rows{64-127,192-255}@P3.
// vmcnt(8) once per tile at P3 (counted; completes tile tt+1, leaves tt+2 in
// flight). Swizzle: LDS[row][c] = global k-chunk c^(row&7), both-sides.

template <int MH, int NH>
__device__ __forceinline__ void quad(f32x4 (&acc)[8][4], short8 (&af)[4][2],
                                     short8 (&bf)[2][2]) {
  __builtin_amdgcn_s_setprio(1);
#pragma unroll
  for (int m = 0; m < 4; ++m)
#pragma unroll
    for (int n = 0; n < 2; ++n)
#pragma unroll
      for (int ks = 0; ks < 2; ++ks)
        mfma_bf16(acc[MH * 4 + m][NH * 2 + n], af[m][ks], bf[n][ks]);
  __builtin_amdgcn_s_setprio(0);
}

__global__ __launch_bounds__(512, 2) void gemm256(
    const unsigned short* __restrict__ A, const unsigned short* __restrict__ B,
    float* __restrict__ C, int M, int N, int K) {
  __shared__ __align__(16) unsigned short As[2 * 16384];  // 2 buf x [256][64]
  __shared__ __align__(16) unsigned short Bs[2 * 16384];

  const int mtiles = M >> 8;
  const int nwg = gridDim.x;
  const int bid = blockIdx.x;
  const int swz = (bid & 7) * (nwg >> 3) + (bid >> 3);  // nwg % 8 == 0
  const int tm = swz % mtiles, tn = swz / mtiles;
  const size_t m0 = (size_t)tm * 256, n0 = (size_t)tn * 256;
  const size_t Kz = (size_t)K, Nz = (size_t)N;

  const int t = threadIdx.x;
  const int w = t >> 6, lane = t & 63;
  const int wr = w >> 2, wc = w & 3;
  const int l15 = lane & 15, l4 = lane >> 4;

  // staging: one gload = 64 rows; thread t owns 16B chunk t of the region:
  // region row = t>>3, chunk col = t&7, source k-chunk = col ^ (row&7).
  const int srow = t >> 3;
  const int cg = ((t & 7) ^ (srow & 7)) * 8;
  const unsigned short* gA = A + (m0 + srow) * Kz + cg;
  const unsigned short* gB = B + (n0 + srow) * Kz + cg;

  auto stgA = [&](int r0, int tt) {  // rows [r0, r0+64) of A tile tt
    gload_lds16(gA + (size_t)r0 * Kz + (size_t)tt * 64,
                (unsigned short*)As + (tt & 1) * 16384 + r0 * 64 + w * 512);
  };
  auto stgB = [&](int r0, int tt) {
    gload_lds16(gB + (size_t)r0 * Kz + (size_t)tt * 64,
                (unsigned short*)Bs + (tt & 1) * 16384 + r0 * 64 + w * 512);
  };

  // frag reads (swizzled): chunk' = (ks*4 + l4) ^ (row&7), row&7 == l15&7
  const int c0s = (l4 ^ (l15 & 7)) * 8;
  const int c1s = ((4 + l4) ^ (l15 & 7)) * 8;
  const int aRow = (wr * 128 + l15) * 64;
  const int bRow = (wc * 64 + l15) * 64;

  auto loadA = [&](const unsigned short* Ab, int mh, short8 (&af)[4][2]) {
#pragma unroll
    for (int m = 0; m < 4; ++m) {
      const unsigned short* p = Ab + aRow + (mh * 64 + m * 16) * 64;
      af[m][0] = *reinterpret_cast<const short8*>(p + c0s);
      af[m][1] = *reinterpret_cast<const short8*>(p + c1s);
    }
  };
  auto loadB = [&](const unsigned short* Bb, int nh, short8 (&bf)[2][2]) {
#pragma unroll
    for (int n = 0; n < 2; ++n) {
      const unsigned short* p = Bb + bRow + (nh * 32 + n * 16) * 64;
      bf[n][0] = *reinterpret_cast<const short8*>(p + c0s);
      bf[n][1] = *reinterpret_cast<const short8*>(p + c1s);
    }
  };

  auto barMid = [&]() {
    __builtin_amdgcn_sched_barrier(0);
    __builtin_amdgcn_s_barrier();
    asm volatile("s_waitcnt lgkmcnt(0)" ::: "memory");
    __builtin_amdgcn_sched_barrier(0);
  };
  auto barEnd = [&]() {
    __builtin_amdgcn_sched_barrier(0);
    __builtin_amdgcn_s_barrier();
  };

  f32x4 acc[8][4] = {};
  short8 af[4][2], bf0[2][2], bf0n[2][2], bf1[2][2];

  const int T = K >> 6;
  // prologue: tile 0 (8 gloads) | fence | tile 1 (8 gloads) | vmcnt(8)
  stgA(0, 0); stgA(64, 0); stgA(128, 0); stgA(192, 0);
  stgB(0, 0); stgB(64, 0); stgB(128, 0); stgB(192, 0);
  memfence_ir();
  stgA(0, 1); stgA(64, 1); stgA(128, 1); stgA(192, 1);
  stgB(0, 1); stgB(64, 1); stgB(128, 1); stgB(192, 1);
  asm volatile("s_waitcnt vmcnt(8)" ::: "memory");  // tile 0 fully landed
  __builtin_amdgcn_s_barrier();
  loadB((const unsigned short*)Bs, 0, bf0);  // prime B-nh0 of tile 0

  for (int tt = 0; tt < T; ++tt) {
    const unsigned short* Ab = (const unsigned short*)As + (tt & 1) * 16384;
    const unsigned short* Bb = (const unsigned short*)Bs + (tt & 1) * 16384;
    const unsigned short* Bbn = (const unsigned short*)Bs + ((tt + 1) & 1) * 16384;
    // P0: reads A-mh0 (8); bf0 already in regs
    loadA(Ab, 0, af);
    barMid();
    quad<0, 0>(acc, af, bf0);
    barEnd();
    // P1: reads B-nh1 (4); stage A rows 0-63 & 128-191 of tt+2 (last read: P0)
    loadB(Bb, 1, bf1);
    if (tt + 2 < T) { stgA(0, tt + 2); stgA(128, tt + 2); }
    barMid();
    quad<0, 1>(acc, af, bf1);
    barEnd();
    // P2: reads A-mh1 (8); stage all B quarters of tt+2 (last read: P1)
    loadA(Ab, 1, af);
    if (tt + 2 < T) { stgB(0, tt + 2); stgB(64, tt + 2); stgB(128, tt + 2); stgB(192, tt + 2); }
    barMid();
    quad<1, 1>(acc, af, bf1);
    barEnd();
    // P3: stage A rows 64-127 & 192-255 of tt+2 (last read: P2); per-tile
    // counted vmcnt; then prefetch next tile's B-nh0 under this phase's MFMA.
    if (tt + 2 < T) {
      stgA(64, tt + 2); stgA(192, tt + 2);
      asm volatile("s_waitcnt vmcnt(8)" ::: "memory");  // tile tt+1 landed
    } else if (tt + 1 < T) {
      asm volatile("s_waitcnt vmcnt(0)" ::: "memory");  // tail drain
    }
    barMid();
    if (tt + 1 < T) loadB(Bbn, 0, bf0n);  // legal: post vmcnt+barrier
    __builtin_amdgcn_sched_barrier(0);
    quad<1, 0>(acc, af, bf0);
    if (tt + 1 < T) {
#pragma unroll
      for (int n = 0; n < 2; ++n) { bf0[n][0] = bf0n[n][0]; bf0[n][1] = bf0n[n][1]; }
    }
    barEnd();
  }

  // epilogue: row = m0+wr*128+mh*64+m*16+l4*4+r, col = n0+wc*64+nh*32+n*16+l15
#pragma unroll
  for (int mh = 0; mh < 2; ++mh)
#pragma unroll
    for (int m = 0; m < 4; ++m) {
      size_t r0 = m0 + wr * 128 + mh * 64 + m * 16 + l4 * 4;
#pragma unroll
      for (int nh = 0; nh < 2; ++nh)
#pragma unroll
        for (int n = 0; n < 2; ++n) {
          size_t c0 = n0 + wc * 64 + nh * 32 + n * 16 + l15;
          float* cp = C + r0 * Nz + c0;
#pragma unroll
          for (int r = 0; r < 4; ++r) cp[(size_t)r * Nz] = acc[mh * 4 + m][nh * 2 + n][r];
        }
    }
}

// ---------- kernel 3: column softmax via Gram symmetry -> bt (bf16, bt[j][i]=b[i][j]) ----------

__global__ __launch_bounds__(256) void softmax_rows(
    const float* __restrict__ a, unsigned short* __restrict__ bt) {
  const int D = 4096;
  const int row = blockIdx.x;
  const float* ar = a + (size_t)row * D;
  unsigned short* br = bt + (size_t)row * D;
  const int t = threadIdx.x;

  float4v v[4];
  float mx = -3.4e38f;
#pragma unroll
  for (int p = 0; p < 4; ++p) {
    v[p] = *reinterpret_cast<const float4v*>(&ar[p * 1024 + t * 4]);
#pragma unroll
    for (int q = 0; q < 4; ++q) mx = fmaxf(mx, v[p][q]);
  }
#pragma unroll
  for (int o = 32; o >= 1; o >>= 1) mx = fmaxf(mx, __shfl_xor(mx, o));
  __shared__ float redm[4], reds[4];
  if ((t & 63) == 0) redm[t >> 6] = mx;
  __syncthreads();
  mx = fmaxf(fmaxf(redm[0], redm[1]), fmaxf(redm[2], redm[3]));

  float e[16];
  float s = 0.f;
#pragma unroll
  for (int p = 0; p < 4; ++p)
#pragma unroll
    for (int q = 0; q < 4; ++q) {
      float ev = __expf(v[p][q] - mx);
      e[p * 4 + q] = ev;
      s += ev;
    }
#pragma unroll
  for (int o = 32; o >= 1; o >>= 1) s += __shfl_xor(s, o);
  if ((t & 63) == 0) reds[t >> 6] = s;
  __syncthreads();
  s = reds[0] + reds[1] + reds[2] + reds[3];
  float inv = 1.0f / s;

#pragma unroll
  for (int p = 0; p < 4; ++p) {
    ushort4v o4;
#pragma unroll
    for (int q = 0; q < 4; ++q) o4[q] = f2bf(e[p * 4 + q] * inv);
    *reinterpret_cast<ushort4v*>(&br[p * 1024 + t * 4]) = o4;
  }
}

// ---------- launch ----------

extern "C" void kernel_launch(void* const* d_in, const int* in_sizes, int n_in,
                              void* d_out, int out_size, void* d_ws, size_t ws_size,
                              hipStream_t stream) {
  const int N = 8192, D = 4096;
  const float* x = (const float*)d_in[0];
  float* out = (float*)d_out;
  uint8_t* ws = (uint8_t*)d_ws;

  unsigned short* xt = (unsigned short*)ws;                           // 64 MB bf16 [D][N]
  unsigned short* xb = (unsigned short*)(ws + ((size_t)64 << 20));    // 64 MB bf16 [N][D]
  unsigned short* bt = (unsigned short*)(ws + ((size_t)128 << 20));   // 32 MB bf16 [D][D]
  float* a = out;  // Gram matrix staged in d_out (overwritten by GEMM2)

  transpose_convert<<<dim3(D / 32, N / 32), dim3(32, 8), 0, stream>>>(x, xt, xb);
  gemm256<<<dim3((D / 256) * (D / 256)), dim3(512), 0, stream>>>(xt, xt, a, D, D, N);
  softmax_rows<<<dim3(D), dim3(256), 0, stream>>>(a, bt);
  gemm256<<<dim3((N / 256) * (D / 256)), dim3(512), 0, stream>>>(xb, bt, out, N, D, D);
}